// Round 4
// baseline (317.231 us; speedup 1.0000x reference)
//
#include <hip/hip_runtime.h>

#define N_NODES 100000
#define N_EDGES 800000
#define NEG 0.2f
#define PB_SHIFT 8
#define PB_NODES 256
#define N_PBKT ((N_NODES + PB_NODES - 1) / PB_NODES)   // 391
#define TILE_E 1024
#define EPT 4           // edges per thread in partition (TILE_E / 256)
#define PREP_BLOCKS ((N_NODES * 128 / 4 + 255) / 256)  // 12500
#define HIST_BLOCKS 192

typedef __attribute__((ext_vector_type(8))) short bf16x8;
typedef __attribute__((ext_vector_type(4))) float f32x4;

__device__ inline unsigned short f2bf(float f) {   // RNE f32 -> bf16
    unsigned u = __float_as_uint(f);
    u += 0x7fffu + ((u >> 16) & 1u);
    return (unsigned short)(u >> 16);
}
__device__ inline float bf2f_lo(unsigned u) { return __uint_as_float(u << 16); }
__device__ inline float bf2f_hi(unsigned u) { return __uint_as_float(u & 0xffff0000u); }

// ---------------------------------------------------------------------------
// prep_w: pack W (and Aalpha = W·a, ct==8) into MFMA B-fragment order.
// Also zeroes the bucket-count array and the adj end-pads.
// ---------------------------------------------------------------------------
__global__ __launch_bounds__(256) void prep_w_kernel(
    const float* __restrict__ W_in, const float* __restrict__ W_out,
    const float* __restrict__ as_in, const float* __restrict__ ad_in,
    const float* __restrict__ as_out, const float* __restrict__ ad_out,
    unsigned short* __restrict__ Wf, int* __restrict__ bcnt,
    int* __restrict__ adj_in, int* __restrict__ adj_out)
{
    const int t = blockIdx.x * 256 + threadIdx.x;
    if (t < 2 * N_PBKT) bcnt[t] = 0;
    if (t < 8) { adj_in[N_EDGES + t] = 0; adj_out[N_EDGES + t] = 0; }
    if (t >= 2 * 4 * 9 * 64) return;
    const int lane = t & 63;
    const int rest = t >> 6;
    const int ct  = rest % 9;
    const int kb  = (rest / 9) & 3;
    const int dir = rest / 36;
    const float* W  = dir ? W_out  : W_in;
    const float* as = dir ? as_out : as_in;
    const float* ad = dir ? ad_out : ad_in;
    const int m16 = lane & 15, quad = lane >> 4;

    bf16x8 o;
#pragma unroll
    for (int j = 0; j < 8; ++j) {
        const int k = kb * 32 + quad * 8 + j;
        float v;
        if (ct < 8) {
            v = W[k * 128 + ct * 16 + m16];
        } else {
            const float* av = (m16 < 8) ? as : ad;
            const int hh = m16 & 7;
            v = 0.f;
            for (int c = 0; c < 16; ++c)
                v += W[k * 128 + hh * 16 + c] * av[hh * 16 + c];
        }
        o[j] = (short)f2bf(v);
    }
    *(bf16x8*)&Wf[(long long)t * 8] = o;
}

// ---------------------------------------------------------------------------
// fused prep_x + coarse bucket histogram.
// ---------------------------------------------------------------------------
__global__ __launch_bounds__(256) void prep_hist_kernel(
    const float* __restrict__ x, unsigned short* __restrict__ x_bf,
    const int* __restrict__ ei, int* __restrict__ bcnt)
{
    const int tid = threadIdx.x;
    if (blockIdx.x < PREP_BLOCKS) {
        const int i = (blockIdx.x * 256 + tid) * 4;
        if (i >= N_NODES * 128) return;
        const float4 v = *(const float4*)&x[i];
        ushort4 o;
        o.x = f2bf(v.x); o.y = f2bf(v.y); o.z = f2bf(v.z); o.w = f2bf(v.w);
        *(ushort4*)&x_bf[i] = o;
        return;
    }
    // histogram part
    __shared__ int bh[2 * N_PBKT];
    for (int i = tid; i < 2 * N_PBKT; i += 256) bh[i] = 0;
    __syncthreads();
    const int hb = blockIdx.x - PREP_BLOCKS;
    for (int e = hb * 256 + tid; e < N_EDGES; e += HIST_BLOCKS * 256) {
        const int s = ei[e];
        const int t = ei[N_EDGES + e];
        atomicAdd(&bh[t >> PB_SHIFT], 1);               // dir0: group by dst
        atomicAdd(&bh[N_PBKT + (s >> PB_SHIFT)], 1);    // dir1: group by src
    }
    __syncthreads();
    for (int i = tid; i < 2 * N_PBKT; i += 256) {
        const int v = bh[i];
        if (v) atomicAdd(&bcnt[i], v);
    }
}

// ---------------------------------------------------------------------------
// gemm: h = bf16(x) @ bf16(W) via MFMA; alpha logits from the 9th column tile.
// ---------------------------------------------------------------------------
__global__ __launch_bounds__(256) void gemm_kernel(
    const unsigned short* __restrict__ x_bf,
    const unsigned short* __restrict__ Wf,
    unsigned short* __restrict__ h_in, unsigned short* __restrict__ h_out,
    float* __restrict__ asrc_in, float* __restrict__ adst_in,
    float* __restrict__ asrc_out, float* __restrict__ adst_out)
{
    const int dir = blockIdx.y;
    unsigned short* h = dir ? h_out : h_in;
    float* asrc = dir ? asrc_out : asrc_in;
    float* adst = dir ? adst_out : adst_in;

    const int tid  = threadIdx.x;
    const int lane = tid & 63;
    const int wave = tid >> 6;
    const int m16  = lane & 15;
    const int quad = lane >> 4;
    const int rbase = blockIdx.x * 128 + wave * 32;

    f32x4 acc[2][8];
    f32x4 acc_a[2];
#pragma unroll
    for (int rt = 0; rt < 2; ++rt) {
        acc_a[rt] = f32x4{0.f, 0.f, 0.f, 0.f};
#pragma unroll
        for (int ct = 0; ct < 8; ++ct)
            acc[rt][ct] = f32x4{0.f, 0.f, 0.f, 0.f};
    }

    const unsigned short* wf = Wf + (long long)dir * 4 * 9 * 64 * 8;

#pragma unroll
    for (int kb = 0; kb < 4; ++kb) {
        const int k0 = kb * 32 + quad * 8;
        bf16x8 a[2];
#pragma unroll
        for (int rt = 0; rt < 2; ++rt) {
            int r = rbase + rt * 16 + m16;
            r = r < N_NODES ? r : N_NODES - 1;   // clamp: stores are guarded
            a[rt] = *(const bf16x8*)&x_bf[(long long)r * 128 + k0];
        }
#pragma unroll
        for (int ct = 0; ct < 9; ++ct) {
            const bf16x8 b = *(const bf16x8*)&wf[(long long)((kb * 9 + ct) * 64 + lane) * 8];
            if (ct < 8) {
                acc[0][ct] = __builtin_amdgcn_mfma_f32_16x16x32_bf16(a[0], b, acc[0][ct], 0, 0, 0);
                acc[1][ct] = __builtin_amdgcn_mfma_f32_16x16x32_bf16(a[1], b, acc[1][ct], 0, 0, 0);
            } else {
                acc_a[0] = __builtin_amdgcn_mfma_f32_16x16x32_bf16(a[0], b, acc_a[0], 0, 0, 0);
                acc_a[1] = __builtin_amdgcn_mfma_f32_16x16x32_bf16(a[1], b, acc_a[1], 0, 0, 0);
            }
        }
    }

#pragma unroll
    for (int rt = 0; rt < 2; ++rt) {
#pragma unroll
        for (int r = 0; r < 4; ++r) {
            const int row = rbase + rt * 16 + quad * 4 + r;
            if (row < N_NODES) {
                unsigned short* hp = &h[(long long)row * 128 + m16];
#pragma unroll
                for (int ct = 0; ct < 8; ++ct)
                    hp[ct * 16] = f2bf(acc[rt][ct][r]);
                const float av = acc_a[rt][r];
                if (m16 < 8) asrc[row * 8 + m16] = av;
                else         adst[row * 8 + (m16 - 8)] = av;
            }
        }
    }
}

// ---------------------------------------------------------------------------
// CSR build: scan bucket counts -> boffs (persistent) + gcur (consumed)
// ---------------------------------------------------------------------------
__global__ __launch_bounds__(512) void bucket_scan_kernel(
    const int* __restrict__ bcnt,
    int* __restrict__ boffs0, int* __restrict__ boffs1,
    int* __restrict__ gcur,
    int* __restrict__ offs_in, int* __restrict__ offs_out)
{
    const int dir = blockIdx.x;
    const int* c = bcnt + dir * N_PBKT;
    int* bo = dir ? boffs1 : boffs0;
    int* gc = gcur + dir * N_PBKT;

    __shared__ int sm[512];
    const int tid = threadIdx.x;
    const int v = (tid < N_PBKT) ? c[tid] : 0;
    sm[tid] = v;
    __syncthreads();
#pragma unroll
    for (int off = 1; off < 512; off <<= 1) {
        int t = (tid >= off) ? sm[tid - off] : 0;
        __syncthreads();
        sm[tid] += t;
        __syncthreads();
    }
    if (tid < N_PBKT) {
        const int excl = sm[tid] - v;
        bo[tid] = excl;
        gc[tid] = excl;
    }
    if (tid == N_PBKT - 1) bo[N_PBKT] = sm[tid];   // == N_EDGES
    if (tid == 0) (dir ? offs_out : offs_in)[N_NODES] = N_EDGES;
}

// partition (merged dirs, small tiles): 1024-edge tiles -> 782 blocks (~3/CU;
// round-3's 4096 tile gave only 196 blocks = 0.77/CU, parallelism-starved).
// Both direction histograms + scatters from ONE read of ei.
__global__ __launch_bounds__(256) void partition_kernel(
    const int* __restrict__ ei, int* __restrict__ gcur,
    int* __restrict__ binned0, int* __restrict__ binned1)
{
    __shared__ int hist0[N_PBKT];
    __shared__ int curs0[N_PBKT];
    __shared__ int hist1[N_PBKT];
    __shared__ int curs1[N_PBKT];
    const int tid = threadIdx.x;
    for (int i = tid; i < N_PBKT; i += 256) { hist0[i] = 0; hist1[i] = 0; }
    __syncthreads();

    const int e0 = blockIdx.x * TILE_E;
    int sv[EPT], tv[EPT];
#pragma unroll
    for (int i = 0; i < EPT; ++i) {
        const int e = e0 + i * 256 + tid;
        if (e < N_EDGES) {
            sv[i] = ei[e];
            tv[i] = ei[N_EDGES + e];
            atomicAdd(&hist0[tv[i] >> PB_SHIFT], 1);   // dir0: group by dst
            atomicAdd(&hist1[sv[i] >> PB_SHIFT], 1);   // dir1: group by src
        } else {
            sv[i] = -1; tv[i] = 0;
        }
    }
    __syncthreads();
    for (int b = tid; b < N_PBKT; b += 256) {
        int c = hist0[b];
        curs0[b] = c ? atomicAdd(&gcur[b], c) : 0;
        c = hist1[b];
        curs1[b] = c ? atomicAdd(&gcur[N_PBKT + b], c) : 0;
    }
    __syncthreads();
#pragma unroll
    for (int i = 0; i < EPT; ++i) {
        if (sv[i] >= 0) {
            int pos = atomicAdd(&curs0[tv[i] >> PB_SHIFT], 1);
            binned0[pos] = (sv[i] << 8) | (tv[i] & (PB_NODES - 1));
            pos = atomicAdd(&curs1[sv[i] >> PB_SHIFT], 1);
            binned1[pos] = (tv[i] << 8) | (sv[i] & (PB_NODES - 1));
        }
    }
}

// place: one block per bucket; fine count+scan+cursors in LDS; adj writes
// land in a contiguous ~8KB region. Pure scatter — no w pipeline.
__global__ __launch_bounds__(256) void place_kernel(
    const int* __restrict__ binned0, const int* __restrict__ binned1,
    const int* __restrict__ boffs0, const int* __restrict__ boffs1,
    int* __restrict__ adj_in, int* __restrict__ adj_out,
    int* __restrict__ offs_in, int* __restrict__ offs_out)
{
    const int b   = blockIdx.x;
    const int dir = blockIdx.y;
    const int* bp = dir ? binned1 : binned0;
    const int* bo = dir ? boffs1  : boffs0;
    int* adj  = dir ? adj_out  : adj_in;
    int* offs = dir ? offs_out : offs_in;

    const int base = b << PB_SHIFT;
    const int beg = bo[b], end = bo[b + 1];
    const int tid = threadIdx.x;

    __shared__ int cnt[PB_NODES];
    __shared__ int sc[PB_NODES];
    __shared__ int cur[PB_NODES];

    cnt[tid] = 0;
    __syncthreads();
    for (int p = beg + tid; p < end; p += 256)
        atomicAdd(&cnt[bp[p] & (PB_NODES - 1)], 1);
    __syncthreads();
    const int v = cnt[tid];
    sc[tid] = v;
    __syncthreads();
#pragma unroll
    for (int off = 1; off < PB_NODES; off <<= 1) {
        int t = (tid >= off) ? sc[tid - off] : 0;
        __syncthreads();
        sc[tid] += t;
        __syncthreads();
    }
    const int excl = beg + sc[tid] - v;
    cur[tid] = excl;
    const int node = base + tid;
    if (node < N_NODES) offs[node] = excl;
    __syncthreads();
    for (int p = beg + tid; p < end; p += 256) {
        const int pk = bp[p];
        adj[atomicAdd(&cur[pk & (PB_NODES - 1)], 1)] = pk >> 8;
    }
}

// ---------------------------------------------------------------------------
// Gather v6: one wave per node, wave-uniform n; DIRECTION-INTERLEAVED main
// loop. The two dirs touch disjoint arrays with independent accumulators, so
// fusing their group-iterations into one body lets both adj loads, both asrc
// gathers and all 16 h-row loads be in flight simultaneously (round-3 ran
// them serially: dir1's chain started cold after dir0 drained). Numerics
// identical to v5 (same per-lane accumulation order within each dir).
// ---------------------------------------------------------------------------
__global__ __launch_bounds__(256) void gather_kernel(
    const int* __restrict__ offs_in, const int* __restrict__ adj_in,
    const int* __restrict__ offs_out, const int* __restrict__ adj_out,
    const unsigned short* __restrict__ h_in, const unsigned short* __restrict__ h_out,
    const float* __restrict__ asrc_in, const float* __restrict__ adst_in,
    const float* __restrict__ asrc_out, const float* __restrict__ adst_out,
    const float* __restrict__ b_in, const float* __restrict__ b_out,
    float* __restrict__ out)
{
    int n = (blockIdx.x * 256 + threadIdx.x) >> 6;
    if (n >= N_NODES) return;
    n = __builtin_amdgcn_readfirstlane(n);
    const int lane = threadIdx.x & 63;
    const int c0 = lane * 2;
    const int hh = lane >> 3;        // head this lane accumulates for
    const int g8 = lane & 7;         // neighbor slot this lane owns
    const int grpbase = lane & 56;   // hh*8: base lane of this head group

    float acc0 = b_in[c0] + b_out[c0];
    float acc1 = b_in[c0 + 1] + b_out[c0 + 1];

    const int beg0 = offs_in[n],  end0 = offs_in[n + 1];
    const int beg1 = offs_out[n], end1 = offs_out[n + 1];
    const float ad0 = adst_in[n * 8 + hh];
    const float ad1 = adst_out[n * 8 + hh];

    float n00 = 0.f, n01 = 0.f, den0 = 0.f;
    float n10 = 0.f, n11 = 0.f, den1 = 0.f;
    int p0 = beg0, p1 = beg1;

#define GRP(ADJ, ASRC, AD, HX, P, END, DEN, NU0, NU1)                          \
    {                                                                          \
        const int nbv = ADJ[P + g8];              /* vector ld, padded */      \
        float l = ASRC[nbv * 8 + hh] + AD;                                     \
        l = l > 0.f ? l : NEG * l;                                             \
        float w = __expf(l);                                                   \
        w = (P + g8 < END) ? w : 0.f;                                          \
        DEN += w;                                                              \
        _Pragma("unroll")                                                      \
        for (int g = 0; g < 8; ++g) {                                          \
            const int nb = ADJ[P + g];            /* scalar (uniform) */       \
            const float w_g = __shfl(w, grpbase + g, 64);                      \
            const unsigned hv = *(const unsigned*)&HX[(long long)nb * 128 + c0]; \
            NU0 += w_g * bf2f_lo(hv);                                          \
            NU1 += w_g * bf2f_hi(hv);                                          \
        }                                                                      \
    }

    while (p0 < end0 && p1 < end1) {
        GRP(adj_in,  asrc_in,  ad0, h_in,  p0, end0, den0, n00, n01)
        GRP(adj_out, asrc_out, ad1, h_out, p1, end1, den1, n10, n11)
        p0 += 8; p1 += 8;
    }
    while (p0 < end0) {
        GRP(adj_in,  asrc_in,  ad0, h_in,  p0, end0, den0, n00, n01)
        p0 += 8;
    }
    while (p1 < end1) {
        GRP(adj_out, asrc_out, ad1, h_out, p1, end1, den1, n10, n11)
        p1 += 8;
    }
#undef GRP

    if (end0 > beg0) {
        den0 += __shfl_xor(den0, 1, 64);
        den0 += __shfl_xor(den0, 2, 64);
        den0 += __shfl_xor(den0, 4, 64);
        const float r = 1.f / den0;
        acc0 += n00 * r;
        acc1 += n01 * r;
    }
    if (end1 > beg1) {
        den1 += __shfl_xor(den1, 1, 64);
        den1 += __shfl_xor(den1, 2, 64);
        den1 += __shfl_xor(den1, 4, 64);
        const float r = 1.f / den1;
        acc0 += n10 * r;
        acc1 += n11 * r;
    }

    *(float2*)&out[(long long)n * 128 + c0] = float2{acc0, acc1};
}

extern "C" void kernel_launch(void* const* d_in, const int* in_sizes, int n_in,
                              void* d_out, int out_size, void* d_ws, size_t ws_size,
                              hipStream_t stream) {
    const float* x      = (const float*)d_in[0];
    const int*   ei     = (const int*)  d_in[1];
    const float* W_in   = (const float*)d_in[2];
    const float* as_in  = (const float*)d_in[3];
    const float* ad_in  = (const float*)d_in[4];
    const float* b_in   = (const float*)d_in[5];
    const float* W_out  = (const float*)d_in[6];
    const float* as_out = (const float*)d_in[7];
    const float* ad_out = (const float*)d_in[8];
    const float* b_out  = (const float*)d_in[9];
    float* out = (float*)d_out;

    char* ws = (char*)d_ws;
    const long long NH = (long long)N_NODES * 128;
    unsigned short* x_bf  = (unsigned short*)ws;    ws += NH * 2;
    unsigned short* h_in  = (unsigned short*)ws;    ws += NH * 2;
    unsigned short* h_out = (unsigned short*)ws;    ws += NH * 2;
    unsigned short* Wf    = (unsigned short*)ws;    ws += 2LL * 4 * 9 * 64 * 8 * 2;
    float* asrc_in   = (float*)ws;                  ws += N_NODES * 8 * 4;
    float* adst_in   = (float*)ws;                  ws += N_NODES * 8 * 4;
    float* asrc_out  = (float*)ws;                  ws += N_NODES * 8 * 4;
    float* adst_out  = (float*)ws;                  ws += N_NODES * 8 * 4;
    int* binned0     = (int*)ws;                    ws += (long long)N_EDGES * 4;
    int* binned1     = (int*)ws;                    ws += (long long)N_EDGES * 4;
    int* adj_in      = (int*)ws;                    ws += (N_EDGES + 8) * 4;
    int* adj_out     = (int*)ws;                    ws += (N_EDGES + 8) * 4;
    int* offs_in     = (int*)ws;                    ws += (N_NODES + 1) * 4;
    int* offs_out    = (int*)ws;                    ws += (N_NODES + 1) * 4;
    int* bcnt        = (int*)ws;                    ws += 2 * N_PBKT * 4;
    int* boffs0      = (int*)ws;                    ws += (N_PBKT + 1) * 4;
    int* boffs1      = (int*)ws;                    ws += (N_PBKT + 1) * 4;
    int* gcur        = (int*)ws;                    ws += 2 * N_PBKT * 4;

    prep_w_kernel<<<(2 * 4 * 9 * 64 + 255) / 256, 256, 0, stream>>>(
        W_in, W_out, as_in, ad_in, as_out, ad_out, Wf, bcnt, adj_in, adj_out);
    prep_hist_kernel<<<PREP_BLOCKS + HIST_BLOCKS, 256, 0, stream>>>(
        x, x_bf, ei, bcnt);

    dim3 gemm_grid((N_NODES + 127) / 128, 2);
    gemm_kernel<<<gemm_grid, 256, 0, stream>>>(
        x_bf, Wf, h_in, h_out, asrc_in, adst_in, asrc_out, adst_out);

    bucket_scan_kernel<<<2, 512, 0, stream>>>(
        bcnt, boffs0, boffs1, gcur, offs_in, offs_out);
    partition_kernel<<<(N_EDGES + TILE_E - 1) / TILE_E, 256, 0, stream>>>(
        ei, gcur, binned0, binned1);
    place_kernel<<<dim3(N_PBKT, 2), 256, 0, stream>>>(
        binned0, binned1, boffs0, boffs1, adj_in, adj_out, offs_in, offs_out);

    gather_kernel<<<(N_NODES * 64 + 255) / 256, 256, 0, stream>>>(
        offs_in, adj_in, offs_out, adj_out, h_in, h_out,
        asrc_in, adst_in, asrc_out, adst_out, b_in, b_out, out);
}